// Round 13
// baseline (433.780 us; speedup 1.0000x reference)
//
#include <hip/hip_runtime.h>
#include <cstdint>
#include <cstddef>

#define NPTS 8192
#define BATCH 16
#define MS 128
#define KNB 64
#define NBLK (BATCH * MS)   // 2048

// ---------------- DPP wave reductions (VALU-speed, no LDS crossbar) ----------
__device__ __forceinline__ float dpp_wave_max_f32(float v) {
  v = fmaxf(v, __int_as_float(__builtin_amdgcn_update_dpp((int)0xff800000, __float_as_int(v), 0x111, 0xf, 0xf, false)));
  v = fmaxf(v, __int_as_float(__builtin_amdgcn_update_dpp((int)0xff800000, __float_as_int(v), 0x112, 0xf, 0xf, false)));
  v = fmaxf(v, __int_as_float(__builtin_amdgcn_update_dpp((int)0xff800000, __float_as_int(v), 0x114, 0xf, 0xf, false)));
  v = fmaxf(v, __int_as_float(__builtin_amdgcn_update_dpp((int)0xff800000, __float_as_int(v), 0x118, 0xf, 0xf, false)));
  v = fmaxf(v, __int_as_float(__builtin_amdgcn_update_dpp((int)0xff800000, __float_as_int(v), 0x142, 0xa, 0xf, false)));
  v = fmaxf(v, __int_as_float(__builtin_amdgcn_update_dpp((int)0xff800000, __float_as_int(v), 0x143, 0xc, 0xf, false)));
  return v;  // lane 63
}

__device__ __forceinline__ float dpp_wave_min_f32(float v) {
  v = fminf(v, __int_as_float(__builtin_amdgcn_update_dpp(0x7f800000, __float_as_int(v), 0x111, 0xf, 0xf, false)));
  v = fminf(v, __int_as_float(__builtin_amdgcn_update_dpp(0x7f800000, __float_as_int(v), 0x112, 0xf, 0xf, false)));
  v = fminf(v, __int_as_float(__builtin_amdgcn_update_dpp(0x7f800000, __float_as_int(v), 0x114, 0xf, 0xf, false)));
  v = fminf(v, __int_as_float(__builtin_amdgcn_update_dpp(0x7f800000, __float_as_int(v), 0x118, 0xf, 0xf, false)));
  v = fminf(v, __int_as_float(__builtin_amdgcn_update_dpp(0x7f800000, __float_as_int(v), 0x142, 0xa, 0xf, false)));
  v = fminf(v, __int_as_float(__builtin_amdgcn_update_dpp(0x7f800000, __float_as_int(v), 0x143, 0xc, 0xf, false)));
  return v;  // lane 63
}

__device__ __forceinline__ unsigned dpp_wave_min_u32(unsigned v) {
  unsigned o;
  o = (unsigned)__builtin_amdgcn_update_dpp((int)0xffffffffu, (int)v, 0x111, 0xf, 0xf, false); v = (o < v) ? o : v;
  o = (unsigned)__builtin_amdgcn_update_dpp((int)0xffffffffu, (int)v, 0x112, 0xf, 0xf, false); v = (o < v) ? o : v;
  o = (unsigned)__builtin_amdgcn_update_dpp((int)0xffffffffu, (int)v, 0x114, 0xf, 0xf, false); v = (o < v) ? o : v;
  o = (unsigned)__builtin_amdgcn_update_dpp((int)0xffffffffu, (int)v, 0x118, 0xf, 0xf, false); v = (o < v) ? o : v;
  o = (unsigned)__builtin_amdgcn_update_dpp((int)0xffffffffu, (int)v, 0x142, 0xa, 0xf, false); v = (o < v) ? o : v;
  o = (unsigned)__builtin_amdgcn_update_dpp((int)0xffffffffu, (int)v, 0x143, 0xc, 0xf, false); v = (o < v) ? o : v;
  return v;  // lane 63
}

__device__ __forceinline__ float dpp_row_max_f32(float v) {  // lane 15 of each row
  v = fmaxf(v, __int_as_float(__builtin_amdgcn_update_dpp((int)0xff800000, __float_as_int(v), 0x111, 0xf, 0xf, false)));
  v = fmaxf(v, __int_as_float(__builtin_amdgcn_update_dpp((int)0xff800000, __float_as_int(v), 0x112, 0xf, 0xf, false)));
  v = fmaxf(v, __int_as_float(__builtin_amdgcn_update_dpp((int)0xff800000, __float_as_int(v), 0x114, 0xf, 0xf, false)));
  v = fmaxf(v, __int_as_float(__builtin_amdgcn_update_dpp((int)0xff800000, __float_as_int(v), 0x118, 0xf, 0xf, false)));
  return v;
}

__device__ __forceinline__ unsigned dpp_row_min_u32(unsigned v) {  // lane 15 of each row
  unsigned o;
  o = (unsigned)__builtin_amdgcn_update_dpp((int)0xffffffffu, (int)v, 0x111, 0xf, 0xf, false); v = (o < v) ? o : v;
  o = (unsigned)__builtin_amdgcn_update_dpp((int)0xffffffffu, (int)v, 0x112, 0xf, 0xf, false); v = (o < v) ? o : v;
  o = (unsigned)__builtin_amdgcn_update_dpp((int)0xffffffffu, (int)v, 0x114, 0xf, 0xf, false); v = (o < v) ? o : v;
  o = (unsigned)__builtin_amdgcn_update_dpp((int)0xffffffffu, (int)v, 0x118, 0xf, 0xf, false); v = (o < v) ? o : v;
  return v;
}

// ---------------------------------------------------------------- FPS
// Frozen structure (~160us floor across 6 variants), now SPLIT into two
// 64-iteration dispatches (md + last-point carried via workspace; bit-identical
// iteration sequence) so the profiler's top-5 exposes the second-tier kernels.
#define FPS_STEP(J)                                                        \
  {                                                                        \
    const float4 p = pts4[J * 1024 + t];                                   \
    const float dx = p.x - lx;                                             \
    const float dy = p.y - ly;                                             \
    const float dz = p.z - lz;                                             \
    const float d = dx * dx + dy * dy + dz * dz;                           \
    md##J = fminf(md##J, d);                                               \
  }

#define FPS_RESCAN(J)                                                      \
  if (md##J == wv) best = (unsigned)(J * 1024 + t);

__global__ __launch_bounds__(1024, 4) void fps_kernel(const float* __restrict__ pos,
                                                      float* __restrict__ sp,
                                                      float* __restrict__ mdst,
                                                      float* __restrict__ lastst,
                                                      int it0) {
#pragma clang fp contract(off)
  extern __shared__ float4 pts4[];  // 8192 * 16B = 128KB dynamic
  __shared__ float wval[2][16];
  __shared__ unsigned widx[2][16];
  const int b = blockIdx.x;
  const float* P = pos + (size_t)b * NPTS * 3;
  const int t = threadIdx.x;
  const int wave = t >> 6;
  const int lane = t & 63;
  float md0, md1, md2, md3, md4, md5, md6, md7;
  for (int i = t; i < NPTS; i += 1024)
    pts4[i] = make_float4(P[i * 3 + 0], P[i * 3 + 1], P[i * 3 + 2], 0.f);
  float lx, ly, lz;
  float* M = mdst + ((size_t)b * 1024 + t) * 8;
  if (it0 == 0) {
    md0 = md1 = md2 = md3 = md4 = md5 = md6 = md7 = 1e10f;
    lx = P[0]; ly = P[1]; lz = P[2];
  } else {
    const float4 a = *reinterpret_cast<const float4*>(M);
    const float4 c = *reinterpret_cast<const float4*>(M + 4);
    md0 = a.x; md1 = a.y; md2 = a.z; md3 = a.w;
    md4 = c.x; md5 = c.y; md6 = c.z; md7 = c.w;
    lx = lastst[b * 4 + 0]; ly = lastst[b * 4 + 1]; lz = lastst[b * 4 + 2];
  }
  __syncthreads();
  for (int it = it0; it < it0 + MS / 2; ++it) {
    if (t == 0) {
      sp[((size_t)b * MS + it) * 3 + 0] = lx;
      sp[((size_t)b * MS + it) * 3 + 1] = ly;
      sp[((size_t)b * MS + it) * 3 + 2] = lz;
    }
    FPS_STEP(0) FPS_STEP(1) FPS_STEP(2) FPS_STEP(3)
    FPS_STEP(4) FPS_STEP(5) FPS_STEP(6) FPS_STEP(7)
    const float m01 = fmaxf(md0, md1), m23 = fmaxf(md2, md3);
    const float m45 = fmaxf(md4, md5), m67 = fmaxf(md6, md7);
    const float bv = fmaxf(fmaxf(m01, m23), fmaxf(m45, m67));
    const float wv = __int_as_float(
        __builtin_amdgcn_readlane(__float_as_int(dpp_wave_max_f32(bv)), 63));
    unsigned best = 0xffffffffu;
    if (bv == wv) {
      FPS_RESCAN(7) FPS_RESCAN(6) FPS_RESCAN(5) FPS_RESCAN(4)
      FPS_RESCAN(3) FPS_RESCAN(2) FPS_RESCAN(1) FPS_RESCAN(0)
    }
    const unsigned wi =
        (unsigned)__builtin_amdgcn_readlane((int)dpp_wave_min_u32(best), 63);
    const int par = it & 1;
    if (lane == 0) { wval[par][wave] = wv; widx[par][wave] = wi; }
    __syncthreads();
    const float a = wval[par][lane & 15];
    const float Mx = __int_as_float(
        __builtin_amdgcn_readlane(__float_as_int(dpp_row_max_f32(a)), 15));
    const unsigned c2 = (a == Mx) ? widx[par][lane & 15] : 0xffffffffu;
    const unsigned idx =
        (unsigned)__builtin_amdgcn_readlane((int)dpp_row_min_u32(c2), 15);
    const float4 c = pts4[idx];
    lx = c.x; ly = c.y; lz = c.z;
  }
  // persist state for the second half
  {
    float4 a, c;
    a.x = md0; a.y = md1; a.z = md2; a.w = md3;
    c.x = md4; c.y = md5; c.z = md6; c.w = md7;
    *reinterpret_cast<float4*>(M) = a;
    *reinterpret_cast<float4*>(M + 4) = c;
    if (t == 0) {
      lastst[b * 4 + 0] = lx;
      lastst[b * 4 + 1] = ly;
      lastst[b * 4 + 2] = lz;
    }
  }
}

// ---------------------------------------------------------------- kNN top-64 v3
// Barrier-free per-wave tournament + exact parallel merge (round-12, verified).
__global__ __launch_bounds__(256) void knn_kernel(const float* __restrict__ pos,
                                                  const float* __restrict__ xf,
                                                  const float* __restrict__ sp,
                                                  float* __restrict__ gf0,
                                                  float* __restrict__ sqsel) {
#pragma clang fp contract(off)
  __shared__ float sqv[NPTS + 32];            // swizzled: addr(i) = i + (i>>8)
  __shared__ unsigned long long wlist[4][KNB];
  __shared__ unsigned long long selk[KNB];
  const int bm = blockIdx.x;
  const int b = bm >> 7;
  const float* P = pos + (size_t)b * NPTS * 3;
  const float sx = sp[bm * 3 + 0], sy = sp[bm * 3 + 1], sz = sp[bm * 3 + 2];
  const float nsp = sx * sx + sy * sy + sz * sz;
  const int t = threadIdx.x;
  const int wave = t >> 6;
  const int lane = t & 63;
  float cv;
  unsigned ci;
  {
    unsigned long long k0 = ~0ULL;
    for (int j = 0; j < 32; ++j) {
      const int i = j * 256 + t;
      const float qx = P[i * 3 + 0], qy = P[i * 3 + 1], qz = P[i * 3 + 2];
      const float npos = qx * qx + qy * qy + qz * qz;
      const float dt = sx * qx + sy * qy + sz * qz;
      float sq = (nsp + npos) - 2.0f * dt;  // matches ||a||^2+||b||^2-2ab order
      sq = fmaxf(sq, 0.0f);
      sqv[i + j] = sq;                      // swizzle: i>>8 == j
      const unsigned long long key =
          ((unsigned long long)__float_as_uint(sq) << 32) | (unsigned)i;
      if (key < k0) k0 = key;
    }
    cv = __uint_as_float((unsigned)(k0 >> 32));
    ci = (unsigned)k0;
  }
  __syncthreads();
  unsigned cmask = 0u;
  for (int round = 0; round < KNB; ++round) {
    const float wv = __int_as_float(
        __builtin_amdgcn_readlane(__float_as_int(dpp_wave_min_f32(cv)), 63));
    const unsigned sel = (cv == wv) ? ci : 0xffffffffu;
    const unsigned wi =
        (unsigned)__builtin_amdgcn_readlane((int)dpp_wave_min_u32(sel), 63);
    if (lane == 0)
      wlist[wave][round] =
          ((unsigned long long)__float_as_uint(wv) << 32) | wi;
    const int col = (int)(wi & 255u);
    const int ownerLane = col & 63;
    const unsigned jsel = wi >> 8;
    if (lane == ownerLane) cmask |= (1u << jsel);
    const unsigned omask =
        (unsigned)__builtin_amdgcn_readlane((int)cmask, ownerLane);
    float v = __uint_as_float(0x7f800000u);
    unsigned ii = 0xffffffffu;
    if (lane < 32 && !((omask >> lane) & 1u)) {
      const int i = lane * 256 + col;
      v = sqv[i + lane];
      ii = (unsigned)i;
    }
    const float mv = __int_as_float(
        __builtin_amdgcn_readlane(__float_as_int(dpp_wave_min_f32(v)), 63));
    const unsigned s2 = (v == mv) ? ii : 0xffffffffu;
    const unsigned mi =
        (unsigned)__builtin_amdgcn_readlane((int)dpp_wave_min_u32(s2), 63);
    if (lane == ownerLane) { cv = mv; ci = mi; }
  }
  __syncthreads();
  {
    const int w = wave, r = lane;
    const unsigned long long e = wlist[w][r];
    int rank = r;
#pragma unroll
    for (int w2 = 0; w2 < 4; ++w2) {
      if (w2 == w) continue;
      int lo = 0;
#pragma unroll
      for (int step = 32; step > 0; step >>= 1)
        if (lo + step <= KNB && wlist[w2][lo + step - 1] < e) lo += step;
      rank += lo;
    }
    if (rank < KNB) selk[rank] = e;
  }
  __syncthreads();
  if (t < KNB) {
    const unsigned long long e = selk[t];
    const int i = (int)(e & 0xffffffffu);
    const float* X = xf + (size_t)b * NPTS * 3;
    const size_t base = ((size_t)bm * KNB + t) * 6;
    gf0[base + 0] = P[i * 3 + 0] - sx;
    gf0[base + 1] = P[i * 3 + 1] - sy;
    gf0[base + 2] = P[i * 3 + 2] - sz;
    gf0[base + 3] = X[i * 3 + 0];
    gf0[base + 4] = X[i * 3 + 1];
    gf0[base + 5] = X[i * 3 + 2];
    sqsel[(size_t)bm * KNB + t] = __uint_as_float((unsigned)(e >> 32));
  }
}

// ================================================================ chain
__global__ __launch_bounds__(256) void l1_kernel(
    const float* __restrict__ gf0, const float* __restrict__ W0,
    const float* __restrict__ B0,
    float* __restrict__ psum, float* __restrict__ psq,
    float* __restrict__ y1pre) {
  __shared__ float in6[64 * 8];
  __shared__ float wbuf[384];
  __shared__ float out[64 * 65];
  const int blk = blockIdx.x;
  const int t = threadIdx.x;
  const float* G = gf0 + (size_t)blk * 384;
  for (int i = t; i < 384; i += 256) in6[(i / 6) * 8 + (i % 6)] = G[i];
  for (int i = t; i < 384; i += 256) wbuf[i] = W0[i];
  __syncthreads();
  const int r = t >> 2;
  const int c0 = (t & 3) * 16;
  float acc[16];
#pragma unroll
  for (int j = 0; j < 16; ++j) acc[j] = B0[c0 + j];
  for (int cin = 0; cin < 6; ++cin) {
    const float a = in6[r * 8 + cin];
#pragma unroll
    for (int j = 0; j < 16; ++j) acc[j] = fmaf(a, wbuf[cin * 64 + c0 + j], acc[j]);
  }
#pragma unroll
  for (int j = 0; j < 16; ++j) out[r * 65 + c0 + j] = acc[j];
  __syncthreads();
  if (t < 64) {
    float s = 0.f, q = 0.f;
    for (int r2 = 0; r2 < 64; ++r2) { const float v = out[r2 * 65 + t]; s += v; q += v * v; }
    psum[(size_t)t * NBLK + blk] = s;
    psq[(size_t)t * NBLK + blk] = q;
  }
  float* Y = y1pre + (size_t)blk * 4096;
  for (int i = t; i < 4096; i += 256) Y[i] = out[(i >> 6) * 65 + (i & 63)];
}

__global__ __launch_bounds__(256) void l2_kernel(
    const float* __restrict__ ypre, const float* __restrict__ sc,
    const float* __restrict__ sh, const float* __restrict__ W1,
    const float* __restrict__ B1,
    float* __restrict__ psum, float* __restrict__ psq,
    float* __restrict__ yout) {
  __shared__ float As[64 * 68];
  __shared__ float Bs[64 * 64];
  __shared__ float out[64 * 68];
  const int blk = blockIdx.x;
  const int t = threadIdx.x;
  const float* Y = ypre + (size_t)blk * 4096;
  for (int i = t; i < 4096; i += 256) {
    const int c = i & 63;
    As[(i >> 6) * 68 + c] = fmaxf(fmaf(Y[i], sc[c], sh[c]), 0.f);
  }
  for (int i = t; i < 4096; i += 256) Bs[i] = W1[i];
  __syncthreads();
  const int tr = t >> 4;
  const int tc4 = (t & 15) * 4;
  float acc[4][4];
#pragma unroll
  for (int s = 0; s < 4; ++s)
#pragma unroll
    for (int j = 0; j < 4; ++j) acc[s][j] = B1[tc4 + j];
  for (int k0 = 0; k0 < 64; k0 += 4) {
    float4 av[4];
#pragma unroll
    for (int s = 0; s < 4; ++s)
      av[s] = *reinterpret_cast<const float4*>(&As[(tr + 16 * s) * 68 + k0]);
#pragma unroll
    for (int kk = 0; kk < 4; ++kk) {
      const float4 bv = *reinterpret_cast<const float4*>(&Bs[(k0 + kk) * 64 + tc4]);
#pragma unroll
      for (int s = 0; s < 4; ++s) {
        const float a = (kk == 0) ? av[s].x : (kk == 1) ? av[s].y
                       : (kk == 2) ? av[s].z : av[s].w;
        acc[s][0] = fmaf(a, bv.x, acc[s][0]);
        acc[s][1] = fmaf(a, bv.y, acc[s][1]);
        acc[s][2] = fmaf(a, bv.z, acc[s][2]);
        acc[s][3] = fmaf(a, bv.w, acc[s][3]);
      }
    }
  }
#pragma unroll
  for (int s = 0; s < 4; ++s) {
    float4 o;
    o.x = acc[s][0]; o.y = acc[s][1]; o.z = acc[s][2]; o.w = acc[s][3];
    *reinterpret_cast<float4*>(&out[(tr + 16 * s) * 68 + tc4]) = o;
  }
  __syncthreads();
  if (t < 64) {
    float s = 0.f, q = 0.f;
    for (int r2 = 0; r2 < 64; ++r2) { const float v = out[r2 * 68 + t]; s += v; q += v * v; }
    psum[(size_t)t * NBLK + blk] = s;
    psq[(size_t)t * NBLK + blk] = q;
  }
  float* O = yout + (size_t)blk * 4096;
  for (int i = t; i < 4096; i += 256) O[i] = out[(i >> 6) * 68 + (i & 63)];
}

__global__ __launch_bounds__(256) void l3_kernel(
    const float* __restrict__ ypre, const float* __restrict__ sc,
    const float* __restrict__ sh, const float* __restrict__ W2,
    const float* __restrict__ B2,
    float* __restrict__ psum, float* __restrict__ psq,
    float* __restrict__ yout) {
  __shared__ float As[64 * 68];
  __shared__ float Bs[64 * 64];
  __shared__ float out[64 * 68];
  const int blk = blockIdx.x;
  const int t = threadIdx.x;
  const float* Y = ypre + (size_t)blk * 4096;
  for (int i = t; i < 4096; i += 256) {
    const int c = i & 63;
    As[(i >> 6) * 68 + c] = fmaxf(fmaf(Y[i], sc[c], sh[c]), 0.f);
  }
  const int tr = t >> 4;
  const int tc4 = (t & 15) * 4;
  for (int hc = 0; hc < 2; ++hc) {
    __syncthreads();
    for (int i = t; i < 4096; i += 256)
      Bs[i] = W2[(i >> 6) * 128 + hc * 64 + (i & 63)];
    __syncthreads();
    float acc[4][4];
#pragma unroll
    for (int s = 0; s < 4; ++s)
#pragma unroll
      for (int j = 0; j < 4; ++j) acc[s][j] = B2[hc * 64 + tc4 + j];
    for (int k0 = 0; k0 < 64; k0 += 4) {
      float4 av[4];
#pragma unroll
      for (int s = 0; s < 4; ++s)
        av[s] = *reinterpret_cast<const float4*>(&As[(tr + 16 * s) * 68 + k0]);
#pragma unroll
      for (int kk = 0; kk < 4; ++kk) {
        const float4 bv = *reinterpret_cast<const float4*>(&Bs[(k0 + kk) * 64 + tc4]);
#pragma unroll
        for (int s = 0; s < 4; ++s) {
          const float a = (kk == 0) ? av[s].x : (kk == 1) ? av[s].y
                         : (kk == 2) ? av[s].z : av[s].w;
          acc[s][0] = fmaf(a, bv.x, acc[s][0]);
          acc[s][1] = fmaf(a, bv.y, acc[s][1]);
          acc[s][2] = fmaf(a, bv.z, acc[s][2]);
          acc[s][3] = fmaf(a, bv.w, acc[s][3]);
        }
      }
    }
#pragma unroll
    for (int s = 0; s < 4; ++s) {
      float4 o;
      o.x = acc[s][0]; o.y = acc[s][1]; o.z = acc[s][2]; o.w = acc[s][3];
      *reinterpret_cast<float4*>(&out[(tr + 16 * s) * 68 + tc4]) = o;
    }
    __syncthreads();
    if (t < 64) {
      float s = 0.f, q = 0.f;
      for (int r2 = 0; r2 < 64; ++r2) { const float v = out[r2 * 68 + t]; s += v; q += v * v; }
      psum[(size_t)(hc * 64 + t) * NBLK + blk] = s;
      psq[(size_t)(hc * 64 + t) * NBLK + blk] = q;
    }
    float* O = yout + (size_t)blk * 8192;
    for (int i = t; i < 4096; i += 256)
      O[(i >> 6) * 128 + hc * 64 + (i & 63)] = out[(i >> 6) * 68 + (i & 63)];
  }
}

// l4+s1 fused: BN3+ReLU+mask+max per channel (x1 row in registers) feeds
// directly into the stage-1 first conv (identical fmaf order to old s1).
__global__ __launch_bounds__(128) void l4s1_kernel(
    const float* __restrict__ y3pre, const float* __restrict__ sc3,
    const float* __restrict__ sh3, const float* __restrict__ sqsel,
    const float* __restrict__ sp, const float* __restrict__ W,
    const float* __restrict__ bia, float* __restrict__ y1) {
  __shared__ float sqs[64];
  __shared__ float row[132];
  const int blk = blockIdx.x;
  const int t = threadIdx.x;
  if (t < 64) sqs[t] = sqsel[(size_t)blk * 64 + t];
  __syncthreads();
  const float scv = sc3[t], shv = sh3[t];
  const float* Y = y3pre + (size_t)blk * 8192;
  float mx = -1e8f;
  for (int r = 0; r < 64; ++r) {
    const float act = fmaxf(fmaf(Y[r * 128 + t], scv, shv), 0.f);
    const float v = (sqs[r] <= 0.16f) ? act : -1e8f;
    mx = fmaxf(mx, v);
  }
  if (t < 3) row[t] = sp[(size_t)blk * 3 + t];
  row[3 + t] = mx;
  __syncthreads();
  float acc = bia[t];
  for (int cin = 0; cin < 131; ++cin) acc = fmaf(row[cin], W[(size_t)cin * 128 + t], acc);
  y1[(size_t)blk * 128 + t] = acc;
}

// Parallel deterministic stats reduce: one block per channel, f64 LDS tree.
__global__ __launch_bounds__(256) void p_stats(const float* __restrict__ psum,
                                               const float* __restrict__ psq,
                                               float invN,
                                               const float* __restrict__ g,
                                               const float* __restrict__ be,
                                               float* __restrict__ sc,
                                               float* __restrict__ sh) {
  const int c = blockIdx.x;
  const int t = threadIdx.x;
  double s = 0.0, q = 0.0;
  for (int k = t; k < NBLK; k += 256) {
    s += (double)psum[(size_t)c * NBLK + k];
    q += (double)psq[(size_t)c * NBLK + k];
  }
  __shared__ double ss[256], qq[256];
  ss[t] = s;
  qq[t] = q;
  __syncthreads();
  for (int st = 128; st > 0; st >>= 1) {
    if (t < st) { ss[t] += ss[t + st]; qq[t] += qq[t + st]; }
    __syncthreads();
  }
  if (t == 0) {
    const double mean = ss[0] * (double)invN;
    double var = qq[0] * (double)invN - mean * mean;
    if (var < 0.0) var = 0.0;
    const float scl = (float)((double)g[c] / sqrt(var + 1e-5));
    sc[c] = scl;
    sh[c] = be[c] - (float)mean * scl;
  }
}

// ---------------------------------------------------------------- stage 1
__global__ __launch_bounds__(128) void s2_kernel(const float* __restrict__ y1,
                                                 const float* __restrict__ sc, const float* __restrict__ sh,
                                                 const float* __restrict__ W, const float* __restrict__ bia,
                                                 float* __restrict__ y2) {
  __shared__ float row[128];
  const int rowid = blockIdx.x;
  const int t = threadIdx.x;
  row[t] = fmaxf(fmaf(y1[(size_t)rowid * 128 + t], sc[t], sh[t]), 0.f);
  __syncthreads();
  float acc = bia[t];
  for (int cin = 0; cin < 128; ++cin) acc = fmaf(row[cin], W[(size_t)cin * 128 + t], acc);
  y2[(size_t)rowid * 128 + t] = acc;
}

__global__ __launch_bounds__(256) void s3_kernel(const float* __restrict__ y2,
                                                 const float* __restrict__ sc, const float* __restrict__ sh,
                                                 const float* __restrict__ W, const float* __restrict__ bia,
                                                 float* __restrict__ y3) {
  __shared__ float row[128];
  const int rowid = blockIdx.x;
  const int t = threadIdx.x;
  if (t < 128) row[t] = fmaxf(fmaf(y2[(size_t)rowid * 128 + t], sc[t], sh[t]), 0.f);
  __syncthreads();
  for (int h = 0; h < 2; ++h) {
    const int c = h * 256 + t;
    float acc = bia[c];
    for (int cin = 0; cin < 128; ++cin) acc = fmaf(row[cin], W[(size_t)cin * 512 + c], acc);
    y3[(size_t)rowid * 512 + c] = acc;
  }
}

__global__ __launch_bounds__(256) void s_stats(const float* __restrict__ y, int C, int rows,
                                               const float* __restrict__ g, const float* __restrict__ be,
                                               float* __restrict__ sc, float* __restrict__ sh) {
  const int c = blockIdx.x;
  const int t = threadIdx.x;
  double s = 0.0, q = 0.0;
  for (int r2 = t; r2 < rows; r2 += 256) {
    const double v = (double)y[(size_t)r2 * C + c];
    s += v;
    q += v * v;
  }
  __shared__ double ss[256], qq[256];
  ss[t] = s;
  qq[t] = q;
  __syncthreads();
  for (int st = 128; st > 0; st >>= 1) {
    if (t < st) { ss[t] += ss[t + st]; qq[t] += qq[t + st]; }
    __syncthreads();
  }
  if (t == 0) {
    const double mean = ss[0] / rows;
    double var = qq[0] / rows - mean * mean;
    if (var < 0.0) var = 0.0;
    const float scl = (float)((double)g[c] / sqrt(var + 1e-5));
    sc[c] = scl;
    sh[c] = be[c] - (float)mean * scl;
  }
}

// stats(512) + final fused: phase A = byte-identical stats reduce (same row
// order, f64 tree); phase B = per-batch max of this block's channel (max is
// exactly associative -> bit-identical to the old final_kernel scan).
__global__ __launch_bounds__(256) void s_stats_final(const float* __restrict__ y3,
                                                     const float* __restrict__ g,
                                                     const float* __restrict__ be,
                                                     float* __restrict__ out) {
  const int c = blockIdx.x;
  const int t = threadIdx.x;
  double s = 0.0, q = 0.0;
  for (int r2 = t; r2 < NBLK; r2 += 256) {
    const double v = (double)y3[(size_t)r2 * 512 + c];
    s += v;
    q += v * v;
  }
  __shared__ double ss[256], qq[256];
  __shared__ float sscl, sshv;
  ss[t] = s;
  qq[t] = q;
  __syncthreads();
  for (int st = 128; st > 0; st >>= 1) {
    if (t < st) { ss[t] += ss[t + st]; qq[t] += qq[t + st]; }
    __syncthreads();
  }
  if (t == 0) {
    const double mean = ss[0] / NBLK;
    double var = qq[0] / NBLK - mean * mean;
    if (var < 0.0) var = 0.0;
    const float scl = (float)((double)g[c] / sqrt(var + 1e-5));
    sscl = scl;
    sshv = be[c] - (float)mean * scl;
  }
  __syncthreads();
  const float scl = sscl, shv = sshv;
  // thread t handles rows [t*8, t*8+8) -- all within batch t>>4
  float mx = -3.402823466e+38f;
  for (int k = 0; k < 8; ++k) {
    const int r = t * 8 + k;
    const float v = fmaxf(fmaf(y3[(size_t)r * 512 + c], scl, shv), 0.f);
    mx = fmaxf(mx, v);
  }
  __shared__ float pmax[256];
  pmax[t] = mx;
  __syncthreads();
  if (t < 16) {
    float m = -3.402823466e+38f;
    for (int j = 0; j < 16; ++j) m = fmaxf(m, pmax[t * 16 + j]);
    out[(size_t)t * 512 + c] = m;
  }
  if (c == 0 && t < 48) out[8192 + t] = 0.f;  // pos_out zeros
}

extern "C" void kernel_launch(void* const* d_in, const int* in_sizes, int n_in,
                              void* d_out, int out_size, void* d_ws, size_t ws_size,
                              hipStream_t stream) {
  const float* x    = (const float*)d_in[0];
  const float* pos  = (const float*)d_in[1];
  const float* W00  = (const float*)d_in[2];
  const float* b00  = (const float*)d_in[3];
  const float* g00  = (const float*)d_in[4];
  const float* be00 = (const float*)d_in[5];
  const float* W01  = (const float*)d_in[6];
  const float* b01  = (const float*)d_in[7];
  const float* g01  = (const float*)d_in[8];
  const float* be01 = (const float*)d_in[9];
  const float* W02  = (const float*)d_in[10];
  const float* b02  = (const float*)d_in[11];
  const float* g02  = (const float*)d_in[12];
  const float* be02 = (const float*)d_in[13];
  const float* W10  = (const float*)d_in[14];
  const float* b10  = (const float*)d_in[15];
  const float* g10  = (const float*)d_in[16];
  const float* be10 = (const float*)d_in[17];
  const float* W11  = (const float*)d_in[18];
  const float* b11  = (const float*)d_in[19];
  const float* g11  = (const float*)d_in[20];
  const float* be11 = (const float*)d_in[21];
  const float* W12  = (const float*)d_in[22];
  const float* b12  = (const float*)d_in[23];
  const float* g12  = (const float*)d_in[24];
  const float* be12 = (const float*)d_in[25];

  float* w = (float*)d_ws;
  float* sp    = w;                  // 16*128*3          = 6144
  float* gf0   = sp + 6144;          // 16*128*64*6       = 786432
  float* sqsel = gf0 + 786432;       // 16*128*64         = 131072
  float* x1    = sqsel + 131072;     // 16*128*128        = 262144 (unused now)
  float* parts = x1 + 262144;        // 128*2048*2        = 524288
  float* psum  = parts;              // [c][blk]
  float* psq   = parts + 128 * NBLK; // [c][blk]
  float* st    = parts + 524288;     // stats area        = 2048
  float* sc1 = st + 0,    *sh1 = st + 64;
  float* sc2 = st + 128,  *sh2 = st + 192;
  float* sc3 = st + 256,  *sh3 = st + 384;
  float* t1sc = st + 512, *t1sh = st + 640;
  float* t2sc = st + 768, *t2sh = st + 896;
  float* y1s = st + 2048;            // 2048*128 = 262144
  float* y2s = y1s + 262144;         // 2048*128 = 262144
  float* y3s = y2s + 262144;         // 2048*512 = 1048576
  const size_t BASE = 3284992;                   // end of base layout (floats)
  float* y1pre = w + BASE;                       // 2048*4096 = 8388608
  float* y2pre = y1pre + 8388608;                // 8388608
  float* y3pre = y2pre + 8388608;                // 2048*8192 = 16777216
  float* mdws  = y3pre + 16777216;               // 16*1024*8 = 131072
  float* lastw = mdws + 131072;                  // 64

  fps_kernel<<<BATCH, 1024, NPTS * sizeof(float4), stream>>>(pos, sp, mdws, lastw, 0);
  fps_kernel<<<BATCH, 1024, NPTS * sizeof(float4), stream>>>(pos, sp, mdws, lastw, 64);
  knn_kernel<<<BATCH * MS, 256, 0, stream>>>(pos, x, sp, gf0, sqsel);

  const float invN0 = 1.0f / (float)(NBLK * KNB);  // 1/131072
  l1_kernel<<<NBLK, 256, 0, stream>>>(gf0, W00, b00, psum, psq, y1pre);
  p_stats<<<64, 256, 0, stream>>>(psum, psq, invN0, g00, be00, sc1, sh1);
  l2_kernel<<<NBLK, 256, 0, stream>>>(y1pre, sc1, sh1, W01, b01, psum, psq, y2pre);
  p_stats<<<64, 256, 0, stream>>>(psum, psq, invN0, g01, be01, sc2, sh2);
  l3_kernel<<<NBLK, 256, 0, stream>>>(y2pre, sc2, sh2, W02, b02, psum, psq, y3pre);
  p_stats<<<128, 256, 0, stream>>>(psum, psq, invN0, g02, be02, sc3, sh3);
  l4s1_kernel<<<NBLK, 128, 0, stream>>>(y3pre, sc3, sh3, sqsel, sp, W10, b10, y1s);

  s_stats<<<128, 256, 0, stream>>>(y1s, 128, NBLK, g10, be10, t1sc, t1sh);
  s2_kernel<<<NBLK, 128, 0, stream>>>(y1s, t1sc, t1sh, W11, b11, y2s);
  s_stats<<<128, 256, 0, stream>>>(y2s, 128, NBLK, g11, be11, t2sc, t2sh);
  s3_kernel<<<NBLK, 256, 0, stream>>>(y2s, t2sc, t2sh, W12, b12, y3s);
  s_stats_final<<<512, 256, 0, stream>>>(y3s, g12, be12, (float*)d_out);
}